// Round 10
// baseline (132.858 us; speedup 1.0000x reference)
//
#include <hip/hip_runtime.h>

#define HEIGHT 8

// =================== REAL PIPELINE (exact R4 kernel, best = 37.1 us) ===================
__global__ void __launch_bounds__(512)
roi_rotate_kernel(const float* __restrict__ images,
                  const float* __restrict__ boxes,
                  const int* __restrict__ box_indices,
                  float* __restrict__ crops,
                  float* __restrict__ width_out,
                  int max_width, int Himg, int Wimg)
{
    const int m   = blockIdx.x;
    const int tid = threadIdx.x;
    const int mw  = max_width;
    const int i   = tid / mw;
    const int j   = tid - i * mw;

    const float x1  = boxes[m * 5 + 0];
    const float y1  = boxes[m * 5 + 1];
    const float x2  = boxes[m * 5 + 2];
    const float y2  = boxes[m * 5 + 3];
    const float ang = boxes[m * 5 + 4];
    const float bwd = x2 - x1, bhd = y2 - y1;
    const float width = (float)HEIGHT * bwd / bhd;
    const float cx = (x1 + x2) * 0.5f;
    const float cy = (y1 + y2) * 0.5f;
    const float s  = bhd / (float)HEIGHT;
    const float ca = cosf(ang);
    const float sa = sinf(ang);
    if (tid == 0) width_out[m] = (float)mw - width;

    const float dx = s * ((float)j - (width - 1.0f) * 0.5f);
    const float dy = s * ((float)i - ((float)HEIGHT - 1.0f) * 0.5f);
    const float sx = cx + ca * dx - sa * dy;
    const float sy = cy + sa * dx + ca * dy;

    float v0 = 0.0f, v1 = 0.0f, v2 = 0.0f;

    const bool valid = ((float)j < ceilf(width)) &&
                       (sx >= 0.0f) && (sx <= (float)(Wimg - 1)) &&
                       (sy >= 0.0f) && (sy <= (float)(Himg - 1));

    if (valid) {
        const float x0 = floorf(sx);
        const float y0 = floorf(sy);
        const int x0i = (int)x0;
        const int y0i = (int)y0;
        const int xb  = min(x0i, Wimg - 2);
        const int yb  = min(y0i, Himg - 2);
        // clamped => clamped texel's weight is exactly 0; fold into fx/fy
        const float fx = (x0i == xb) ? (sx - x0) : 1.0f;
        const float fy = (y0i == yb) ? (sy - y0) : 1.0f;

        const int b = box_indices[m];
        const float* img = images + (size_t)b * Himg * Wimg * 3;
        const float* r0  = img + ((size_t)yb * Wimg + xb) * 3;
        const float* r1  = r0 + (size_t)Wimg * 3;
        float s0[6], s1[6];
        __builtin_memcpy(s0, r0, 24);
        __builtin_memcpy(s1, r1, 24);

        const float w00 = (1.0f - fx) * (1.0f - fy);
        const float w01 = fx * (1.0f - fy);
        const float w10 = (1.0f - fx) * fy;
        const float w11 = fx * fy;

        v0 = s0[0] * w00 + s0[3] * w01 + s1[0] * w10 + s1[3] * w11;
        v1 = s0[1] * w00 + s0[4] * w01 + s1[1] * w10 + s1[4] * w11;
        v2 = s0[2] * w00 + s0[5] * w01 + s1[2] * w10 + s1[5] * w11;
    }

    float* o = crops + ((size_t)(m * HEIGHT + i) * mw + j) * 3;
    o[0] = v0; o[1] = v1; o[2] = v2;
}

// =================== prep: params for the diagnostic gather kernel ===================
// params[2m] = {cx, cy, s, (width-1)/2}; params[2m+1] = {ca, sa, ceil(width), img_bits}
__global__ void __launch_bounds__(256)
prep_kernel(const float* __restrict__ boxes,
            const int* __restrict__ box_indices,
            float4* __restrict__ params, int M)
{
    const int m = blockIdx.x * 256 + threadIdx.x;
    if (m >= M) return;
    const float x1  = boxes[m * 5 + 0];
    const float y1  = boxes[m * 5 + 1];
    const float x2  = boxes[m * 5 + 2];
    const float y2  = boxes[m * 5 + 3];
    const float ang = boxes[m * 5 + 4];
    const float bwd = x2 - x1, bhd = y2 - y1;
    const float width = (float)HEIGHT * bwd / bhd;
    params[2 * m]     = make_float4((x1 + x2) * 0.5f, (y1 + y2) * 0.5f,
                                    bhd / (float)HEIGHT, (width - 1.0f) * 0.5f);
    params[2 * m + 1] = make_float4(cosf(ang), sinf(ang), ceilf(width),
                                    __int_as_float(box_indices[m]));
}

// =================== DIAG A: store pattern only, x8 ===================
// Same grid/block/addresses as the real kernel's crop stores, into a d_ws
// mirror. 8 reps; memory clobber prevents rep merging. Measures T_store*8.
__global__ void __launch_bounds__(512)
diag_store_kernel(float* __restrict__ mirror)
{
    const size_t base = ((size_t)blockIdx.x * 512 + threadIdx.x) * 3;
    float* o = mirror + base;
    #pragma unroll 1
    for (int r = 0; r < 8; ++r) {
        o[0] = 0.0f; o[1] = 0.0f; o[2] = 0.0f;
        asm volatile("" ::: "memory");
    }
}

// =================== DIAG B: gather pattern only, x8 ===================
// Same grid/block/addresses/dependency-structure as the real kernel's texel
// gathers + blend; no bulk stores. memory clobber forces re-loads each rep;
// asm keeps acc live on every lane (rule #17). Measures T_gather*8
// (rep 1 DRAM-cold, reps 2-8 L3-warm).
__global__ void __launch_bounds__(512)
diag_gather_kernel(const float* __restrict__ images,
                   const float4* __restrict__ params,
                   float* __restrict__ sink,
                   int Himg, int Wimg)
{
    const int m   = blockIdx.x;
    const int tid = threadIdx.x;
    const int i   = tid >> 6;
    const int j   = tid & 63;

    const float4 pA = params[2 * m];
    const float4 pB = params[2 * m + 1];
    const float cx = pA.x, cy = pA.y, s = pA.z, px = pA.w;
    const float ca = pB.x, sa = pB.y, wlim = pB.z;

    const float dx = s * ((float)j - px);
    const float dy = s * ((float)i - ((float)HEIGHT - 1.0f) * 0.5f);
    const float sx = cx + ca * dx - sa * dy;
    const float sy = cy + sa * dx + ca * dy;

    const bool valid = ((float)j < wlim) &&
                       (sx >= 0.0f) && (sx <= (float)(Wimg - 1)) &&
                       (sy >= 0.0f) && (sy <= (float)(Himg - 1));

    float w00 = 0.f, w01 = 0.f, w10 = 0.f, w11 = 0.f;
    const float* r0 = images;
    const float* r1 = images;
    if (valid) {
        const float x0 = floorf(sx);
        const float y0 = floorf(sy);
        const int x0i = (int)x0;
        const int y0i = (int)y0;
        const int xb  = min(x0i, Wimg - 2);
        const int yb  = min(y0i, Himg - 2);
        const float fx = (x0i == xb) ? (sx - x0) : 1.0f;
        const float fy = (y0i == yb) ? (sy - y0) : 1.0f;
        const float* img = images + (size_t)__float_as_int(pB.w) * Himg * Wimg * 3;
        r0 = img + ((size_t)yb * Wimg + xb) * 3;
        r1 = r0 + (size_t)Wimg * 3;
        w00 = (1.0f - fx) * (1.0f - fy);
        w01 = fx * (1.0f - fy);
        w10 = (1.0f - fx) * fy;
        w11 = fx * fy;
    }

    float acc = 0.0f;
    #pragma unroll 1
    for (int r = 0; r < 8; ++r) {
        if (valid) {
            float s0[6], s1[6];
            __builtin_memcpy(s0, r0, 24);
            __builtin_memcpy(s1, r1, 24);
            acc += s0[0] * w00 + s0[3] * w01 + s1[0] * w10 + s1[3] * w11
                 + s0[1] * w00 + s0[4] * w01 + s1[1] * w10 + s1[4] * w11
                 + s0[2] * w00 + s0[5] * w01 + s1[2] * w10 + s1[5] * w11;
        }
        asm volatile("" : "+v"(acc) : : "memory");   // keep live, force reloads
    }
    if (tid == 0) sink[m] = acc;   // tiny store, keeps kernel effectful
}

extern "C" void kernel_launch(void* const* d_in, const int* in_sizes, int n_in,
                              void* d_out, int out_size, void* d_ws, size_t ws_size,
                              hipStream_t stream) {
    const float* images      = (const float*)d_in[0];
    const float* boxes       = (const float*)d_in[2];
    const int*   box_indices = (const int*)d_in[3];

    const int M  = in_sizes[3];                       // 8192 boxes
    const int mw = (out_size - M) / (M * HEIGHT * 3); // max_width (=64)
    const int Himg = 512, Wimg = 512;

    float* crops     = (float*)d_out;
    float* width_out = crops + (size_t)M * HEIGHT * mw * 3;

    // Real pipeline (identical to R4, the 37.1 us best).
    roi_rotate_kernel<<<M, HEIGHT * mw, 0, stream>>>(
        images, boxes, box_indices, crops, width_out, mw, Himg, Wimg);

    // ---- diagnostics (write only to d_ws; skipped if workspace too small) ----
    const size_t need = (1u << 20) + (size_t)M * 512 * 3 * 4 + (size_t)M * 4 + (1u << 20);
    if (mw == 64 && ws_size >= need) {
        float4* params = (float4*)d_ws;                               // 256 KB
        float*  mirror = (float*)((char*)d_ws + (1u << 20));          // 49.2 MB
        float*  sink   = (float*)((char*)d_ws + (1u << 20)
                                  + (size_t)M * 512 * 3 * 4);         // 32 KB

        prep_kernel<<<(M + 255) / 256, 256, 0, stream>>>(boxes, box_indices, params, M);
        diag_store_kernel<<<M, 512, 0, stream>>>(mirror);
        diag_gather_kernel<<<M, 512, 0, stream>>>(images, params, sink, Himg, Wimg);
    }
}